// Round 5
// baseline (225.408 us; speedup 1.0000x reference)
//
#include <hip/hip_runtime.h>
#include <stdint.h>

// Problem constants: B=4, T=2048, D=1024, NH=16, DH=64
#define TSEQ   2048
#define SCALE_K 0.18033688011112042f   // 0.125 * log2(e): folds attn scale + exp2 domain into K

typedef __attribute__((ext_vector_type(8))) short bf16x8;   // 8 bf16 = 4 VGPRs (MFMA A/B frag)
typedef __attribute__((ext_vector_type(4))) short short4v;
typedef __attribute__((ext_vector_type(4))) float f32x4;    // MFMA C/D frag

#define EXP2F(x) __builtin_amdgcn_exp2f(x)   // v_exp_f32 (HW computes 2^x)

__device__ __forceinline__ short f2bf(float f) {  // RNE float->bf16 (finite inputs)
  unsigned u = __float_as_uint(f);
  u = (u + 0x7fffu + ((u >> 16) & 1u)) >> 16;
  return (short)u;
}

__device__ __forceinline__ void async16(const void* gsrc, void* ldst) {
  __builtin_amdgcn_global_load_lds((__attribute__((address_space(1))) void*)(void*)gsrc,
                                   (__attribute__((address_space(3))) void*)ldst, 16, 0, 0);
}

// ---------------------------------------------------------------------------
// cast fp32 -> bf16 (bits in short), vectorized 4/thread
// ---------------------------------------------------------------------------
__global__ void cast_f32_bf16(const float* __restrict__ src, short* __restrict__ dst, int n) {
  int i = (blockIdx.x * blockDim.x + threadIdx.x) * 4;
  if (i >= n) return;
  float4 v = *(const float4*)(src + i);
  short4v o;
  o[0] = f2bf(v.x); o[1] = f2bf(v.y); o[2] = f2bf(v.z); o[3] = f2bf(v.w);
  *(short4v*)(dst + i) = o;
}

// ---------------------------------------------------------------------------
// C = A[M,K] @ B[N,K]^T  (bf16 in, fp32 acc). 128x128 tile, BK=64, 4 waves.
// MODE 0: C fp32 [M][N] + bias[col].
// MODE 2: qkv-split. cols<1024 (Q) -> bf16 Cqk[row][2048]; 1024..2047 (K) ->
//         bf16 * SCALE_K (log2-domain attn scale); >=2048 (V) -> transposed
//         bf16 to Cvt[(b*16+h)*64+d][2048], t=row%2048.
// ---------------------------------------------------------------------------
template<int MODE>
__global__ __launch_bounds__(256, 2) void gemm_bt(
    const short* __restrict__ A, const short* __restrict__ B,
    void* __restrict__ C, short* __restrict__ Cvt, const float* __restrict__ bias,
    int M, int N, int K)
{
  __shared__ char ldsA[128 * 128];
  __shared__ char ldsB[128 * 128];

  const int tid  = threadIdx.x;
  const int lane = tid & 63;
  const int w    = tid >> 6;
  const int wrow = w >> 1, wcol = w & 1;
  const int l15  = lane & 15;
  const int klo  = (lane >> 4) << 4;

  // XCD-bijective swizzle (m204); nwg%8==0 for both launches
  int nwg = gridDim.x, orig = blockIdx.x;
  int qq = nwg >> 3, rr = nwg & 7;
  int xcd = orig & 7, lid = orig >> 3;
  int wgid = (xcd < rr ? xcd * (qq + 1) : rr * (qq + 1) + (xcd - rr) * qq) + lid;
  const int nbx = N >> 7;
  const int by = wgid / nbx, bx = wgid - by * nbx;
  const int m0 = by << 7, n0 = bx << 7;

  const char* Abase = (const char*)A + (size_t)m0 * K * 2;
  const char* Bbase = (const char*)B + (size_t)n0 * K * 2;
  const int rowstride = K * 2;

  const int srow  = tid >> 3;
  const int scolb = (tid & 7) << 4;

  f32x4 acc[4][4] = {};

  const int nk = K >> 6;
  for (int kk = 0; kk < nk; ++kk) {
    if (kk) __syncthreads();
    const int kbyte = kk << 7;
    #pragma unroll
    for (int p = 0; p < 4; ++p) {
      int row = p * 32 + srow;
      int sc  = scolb ^ ((row & 7) << 4);     // pre-swizzled source (rule #21)
      async16(Abase + (size_t)row * rowstride + kbyte + sc, ldsA + row * 128 + scolb);
      async16(Bbase + (size_t)row * rowstride + kbyte + sc, ldsB + row * 128 + scolb);
    }
    __syncthreads();

    bf16x8 af[2][4], bf[2][4];
    #pragma unroll
    for (int ks = 0; ks < 2; ++ks)
      #pragma unroll
      for (int mi = 0; mi < 4; ++mi) {
        int row = wrow * 64 + mi * 16 + l15;
        af[ks][mi] = *(const bf16x8*)(ldsA + row * 128 + ((ks * 64 + klo) ^ ((row & 7) << 4)));
      }
    #pragma unroll
    for (int ks = 0; ks < 2; ++ks)
      #pragma unroll
      for (int ni = 0; ni < 4; ++ni) {
        int row = wcol * 64 + ni * 16 + l15;
        bf[ks][ni] = *(const bf16x8*)(ldsB + row * 128 + ((ks * 64 + klo) ^ ((row & 7) << 4)));
      }
    #pragma unroll
    for (int mi = 0; mi < 4; ++mi)
      #pragma unroll
      for (int ni = 0; ni < 4; ++ni) {
        acc[mi][ni] = __builtin_amdgcn_mfma_f32_16x16x32_bf16(af[0][mi], bf[0][ni], acc[mi][ni], 0, 0, 0);
        acc[mi][ni] = __builtin_amdgcn_mfma_f32_16x16x32_bf16(af[1][mi], bf[1][ni], acc[mi][ni], 0, 0, 0);
      }
  }

  // epilogue: C/D layout col=lane&15, row=(lane>>4)*4+j  [m89]
  const int rbase = (lane >> 4) << 2;
  #pragma unroll
  for (int mi = 0; mi < 4; ++mi)
    #pragma unroll
    for (int ni = 0; ni < 4; ++ni) {
      const int col  = n0 + wcol * 64 + ni * 16 + l15;
      const int row0 = m0 + wrow * 64 + mi * 16 + rbase;
      if (MODE == 0) {
        #pragma unroll
        for (int j = 0; j < 4; ++j)
          ((float*)C)[(size_t)(row0 + j) * N + col] = acc[mi][ni][j] + bias[col];
      } else {  // MODE 2 (branches are tile-uniform: region boundaries %128==0)
        if (n0 < 1024) {            // Q region
          #pragma unroll
          for (int j = 0; j < 4; ++j)
            ((short*)C)[(size_t)(row0 + j) * 2048 + col] = f2bf(acc[mi][ni][j]);
        } else if (n0 < 2048) {     // K region: fold attn scale + log2e
          #pragma unroll
          for (int j = 0; j < 4; ++j)
            ((short*)C)[(size_t)(row0 + j) * 2048 + col] = f2bf(acc[mi][ni][j] * SCALE_K);
        } else {                    // V region: store transposed Vt[bh*64+d][t]
          short4v o;
          #pragma unroll
          for (int j = 0; j < 4; ++j) o[j] = f2bf(acc[mi][ni][j]);
          const int cv = col - 2048, hh = cv >> 6, dd = cv & 63;
          const int bb = row0 >> 11, t = row0 & 2047;
          *(short4v*)(Cvt + ((size_t)((bb * 16 + hh) * 64 + dd)) * 2048 + t) = o;
        }
      }
    }
}

// ---------------------------------------------------------------------------
// Wave-independent causal flash attention, 4 waves/block. Zero barriers.
// Swapped QK^T (mfma(K,Q)): lane holds S for q-row l15 at 16 kv slots;
// row max/sum = in-lane tree + xor16/xor32 butterfly. S in log2 domain
// (K pre-scaled by 0.125*log2e) -> exp2 directly. P round-trips per-wave
// LDS as vector-of-short (same TBAA family as read) with memory-clobber
// fences BOTH before and after the read (blocks cross-iteration motion).
// ---------------------------------------------------------------------------
__global__ __launch_bounds__(256, 3) void attn_wave(
    const short* __restrict__ qk, const short* __restrict__ vt, short* __restrict__ O)
{
  __shared__ short ldsP[4][32][72];       // per-wave P: [qrow][kv], 144B rows

  const int tid  = threadIdx.x;
  const int lane = tid & 63;
  const int w    = tid >> 6;
  const int l15  = lane & 15;
  const int lg   = lane >> 4;
  short* ldsPw   = &ldsP[w][0][0];

  // Block i: qb = 63 - (i>>4) (longest first, uniform within block);
  // bh-group (i&15): 4 heads per block, 8 groups -> XCD via i&7.
  const int i  = blockIdx.x;              // 0..1023
  const int qb = 63 - (i >> 4);
  const int bh = ((i & 15) << 2) + w;
  const int b  = bh >> 4, h = bh & 15;
  const int q0 = qb * 32;
  const int rowbase = b * TSEQ;

  const short* qbase = qk + (size_t)rowbase * 2048 + h * 64 + lg * 8;
  const short* kbase = qbase + 1024;
  const short* vbase = vt + ((size_t)bh * 64 + l15) * 2048 + lg * 8;

  // Q frags in registers for the whole kernel: Q[q0+qb2*16+l15][ks*32+lg*8..]
  bf16x8 qf[2][2];
  #pragma unroll
  for (int ks = 0; ks < 2; ++ks)
    #pragma unroll
    for (int qb2 = 0; qb2 < 2; ++qb2)
      qf[ks][qb2] = *(const bf16x8*)(qbase + (size_t)(q0 + qb2 * 16 + l15) * 2048 + ks * 32);

  f32x4 oacc[2][4] = {};
  float mrun[2] = {-1e30f, -1e30f}, lrun[2] = {0.f, 0.f};

  const int nst = (qb >> 1) + 1;
  for (int s = 0; s < nst; ++s) {
    const int kv0 = s * 64;

    // K frags: K[kv0+kb*16+l15][ks*32+lg*8..]
    bf16x8 kf[2][4];
    #pragma unroll
    for (int ks = 0; ks < 2; ++ks)
      #pragma unroll
      for (int kb = 0; kb < 4; ++kb)
        kf[ks][kb] = *(const bf16x8*)(kbase + (size_t)(kv0 + kb * 16 + l15) * 2048 + ks * 32);
    // V frags issued early (consumed after softmax -> latency hidden)
    bf16x8 vf[2][4];
    #pragma unroll
    for (int c = 0; c < 2; ++c)
      #pragma unroll
      for (int ni = 0; ni < 4; ++ni)
        vf[c][ni] = *(const bf16x8*)(vbase + (size_t)(ni * 16) * 2048 + kv0 + c * 32);

    // S^T = mfma(K, Q): sacc[kb][qb2][j] = S[q0+qb2*16+l15][kv0+kb*16+lg*4+j]
    f32x4 sacc[4][2] = {};
    #pragma unroll
    for (int kb = 0; kb < 4; ++kb)
      #pragma unroll
      for (int qb2 = 0; qb2 < 2; ++qb2) {
        sacc[kb][qb2] = __builtin_amdgcn_mfma_f32_16x16x32_bf16(kf[0][kb], qf[0][qb2], sacc[kb][qb2], 0, 0, 0);
        sacc[kb][qb2] = __builtin_amdgcn_mfma_f32_16x16x32_bf16(kf[1][kb], qf[1][qb2], sacc[kb][qb2], 0, 0, 0);
      }

    // causal mask (only last tile can touch the diagonal)
    if (s == nst - 1) {
      #pragma unroll
      for (int kb = 0; kb < 4; ++kb)
        #pragma unroll
        for (int qb2 = 0; qb2 < 2; ++qb2) {
          int qrow = q0 + qb2 * 16 + l15;
          #pragma unroll
          for (int j = 0; j < 4; ++j)
            if (kv0 + kb * 16 + lg * 4 + j > qrow) sacc[kb][qb2][j] = -1e30f;
        }
    }

    // online softmax per qb2 (q-row = l15-space), all in log2 domain
    float alpha[2];
    #pragma unroll
    for (int qb2 = 0; qb2 < 2; ++qb2) {
      float t0 = fmaxf(fmaxf(sacc[0][qb2][0], sacc[0][qb2][1]), fmaxf(sacc[0][qb2][2], sacc[0][qb2][3]));
      float t1 = fmaxf(fmaxf(sacc[1][qb2][0], sacc[1][qb2][1]), fmaxf(sacc[1][qb2][2], sacc[1][qb2][3]));
      float t2 = fmaxf(fmaxf(sacc[2][qb2][0], sacc[2][qb2][1]), fmaxf(sacc[2][qb2][2], sacc[2][qb2][3]));
      float t3 = fmaxf(fmaxf(sacc[3][qb2][0], sacc[3][qb2][1]), fmaxf(sacc[3][qb2][2], sacc[3][qb2][3]));
      float v  = fmaxf(fmaxf(t0, t1), fmaxf(t2, t3));
      v = fmaxf(v, __shfl_xor(v, 16));
      v = fmaxf(v, __shfl_xor(v, 32));
      float mold = mrun[qb2];
      float mnew = fmaxf(mold, v);
      alpha[qb2] = EXP2F(mold - mnew);
      mrun[qb2]  = mnew;
      float rs = 0.f;
      #pragma unroll
      for (int kb = 0; kb < 4; ++kb) {
        float p0 = EXP2F(sacc[kb][qb2][0] - mnew);
        float p1 = EXP2F(sacc[kb][qb2][1] - mnew);
        float p2 = EXP2F(sacc[kb][qb2][2] - mnew);
        float p3 = EXP2F(sacc[kb][qb2][3] - mnew);
        rs += (p0 + p1) + (p2 + p3);
        short4v ps;
        ps[0] = f2bf(p0); ps[1] = f2bf(p1); ps[2] = f2bf(p2); ps[3] = f2bf(p3);
        *(short4v*)((char*)ldsPw + (qb2 * 16 + l15) * 144 + kb * 32 + lg * 8) = ps;
      }
      rs += __shfl_xor(rs, 16);
      rs += __shfl_xor(rs, 32);
      lrun[qb2] = lrun[qb2] * alpha[qb2] + rs;
    }

    // redistribute alpha from l15-space to row-space, rescale O
    #pragma unroll
    for (int mi = 0; mi < 2; ++mi)
      #pragma unroll
      for (int j = 0; j < 4; ++j) {
        float ar = __shfl(alpha[mi], lg * 4 + j);
        #pragma unroll
        for (int ni = 0; ni < 4; ++ni) oacc[mi][ni][j] *= ar;
      }

    asm volatile("" ::: "memory");        // fence: P stores complete before P loads

    // O += P @ V
    bf16x8 pf[2][2];
    #pragma unroll
    for (int c = 0; c < 2; ++c)
      #pragma unroll
      for (int mi = 0; mi < 2; ++mi)
        pf[c][mi] = *(const bf16x8*)((const char*)ldsPw + (mi * 16 + l15) * 144 + c * 64 + lg * 16);

    asm volatile("" ::: "memory");        // fence: next iter's P stores can't float above these loads

    #pragma unroll
    for (int mi = 0; mi < 2; ++mi)
      #pragma unroll
      for (int ni = 0; ni < 4; ++ni) {
        oacc[mi][ni] = __builtin_amdgcn_mfma_f32_16x16x32_bf16(pf[0][mi], vf[0][ni], oacc[mi][ni], 0, 0, 0);
        oacc[mi][ni] = __builtin_amdgcn_mfma_f32_16x16x32_bf16(pf[1][mi], vf[1][ni], oacc[mi][ni], 0, 0, 0);
      }
  }

  // epilogue: O[b*T+t][h*64+dh] = oacc / l  (l redistributed l15->row space)
  #pragma unroll
  for (int mi = 0; mi < 2; ++mi) {
    float linv = 1.0f / lrun[mi];
    #pragma unroll
    for (int j = 0; j < 4; ++j) {
      float lr = __shfl(linv, lg * 4 + j);
      int trow = rowbase + q0 + mi * 16 + lg * 4 + j;
      #pragma unroll
      for (int ni = 0; ni < 4; ++ni) {
        int col = h * 64 + ni * 16 + l15;
        O[(size_t)trow * 1024 + col] = f2bf(oacc[mi][ni][j] * lr);
      }
    }
  }
}

// ---------------------------------------------------------------------------
extern "C" void kernel_launch(void* const* d_in, const int* in_sizes, int n_in,
                              void* d_out, int out_size, void* d_ws, size_t ws_size,
                              hipStream_t stream) {
  const float* x     = (const float*)d_in[0];   // [4,2048,1024]
  const float* qkv_w = (const float*)d_in[1];   // [3072,1024]
  const float* o_w   = (const float*)d_in[2];   // [1024,1024]
  const float* o_b   = (const float*)d_in[3];   // [1024]

  char* ws = (char*)d_ws;
  short* xb    = (short*)(ws);                   // 16 MB  [8192][1024] bf16
  short* wqkvb = (short*)(ws + 16777216);        //  6 MB  [3072][1024]
  short* wob   = (short*)(ws + 23068672);        //  2 MB  [1024][1024]
  short* qkb   = (short*)(ws + 25165824);        // 32 MB  [8192][2048]  Q|K
  short* vtb   = (short*)(ws + 58720256);        // 16 MB  [64*64][2048] V^T
  short* ob    = (short*)(ws + 75497472);        // 16 MB  [8192][1024]  attn out

  cast_f32_bf16<<<8192, 256, 0, stream>>>(x,     xb,    8388608);
  cast_f32_bf16<<<3072, 256, 0, stream>>>(qkv_w, wqkvb, 3145728);
  cast_f32_bf16<<<1024, 256, 0, stream>>>(o_w,   wob,   1048576);

  // qkv = x @ qkv_w^T : M=8192, N=3072, K=1024; Q|K row-major (K scaled), V transposed
  gemm_bt<2><<<1536, 256, 0, stream>>>(xb, wqkvb, (void*)qkb, vtb, nullptr, 8192, 3072, 1024);

  attn_wave<<<1024, 256, 0, stream>>>(qkb, vtb, ob);

  // out = attn_out @ o_w^T + o_b : M=8192, N=1024, K=1024
  gemm_bt<0><<<512, 256, 0, stream>>>(ob, wob, d_out, nullptr, o_b, 8192, 1024, 1024);
}